// Round 4
// baseline (45.374 us; speedup 1.0000x reference)
//
#include <hip/hip_runtime.h>

// OKLab -> ACEScg: per-pixel 3-vector transform on [B=8, C=3, H=1024, W=1024] fp32.
// Memory-bound: ~201 MB touched, practical copy ceiling 6.29 TB/s -> ~32 us.
// R3: adjacent-pair quads per thread -> 2 KB contiguous per wave per stream
//     (longer HBM bursts), 6 loads in flight, NT stores kept.

#define HW (1024 * 1024)
#define QP (HW / 4)                 // float4 quads per plane = 2^18
#define NQUADS (8 * QP)             // total pixel-quads = 2^21
#define NTHREADS (NQUADS / 2)       // 2 adjacent quads per thread = 2^20

typedef float f4 __attribute__((ext_vector_type(4)));

struct Px { float r, g, b; };

__device__ __forceinline__ Px oklab_px(float L, float A, float Bv) {
    // y = x @ M1  (row-vector: y_j = sum_i x_i * M1[i][j])
    float y0 = fmaf(0.2158037573f,  Bv, fmaf(0.3963377774f,  A, L));
    float y1 = fmaf(-0.0638541728f, Bv, fmaf(-0.1055613458f, A, L));
    float y2 = fmaf(-1.291485548f,  Bv, fmaf(-0.0894841775f, A, L));

    // signed cube == plain cube
    float l = y0 * y0 * y0;
    float m = y1 * y1 * y1;
    float s = y2 * y2 * y2;

    // z = y @ M2
    float z0 = fmaf(0.2309699292f, s, fmaf(-3.3077115913f, m, 4.0767416621f  * l));
    float z1 = fmaf(-0.3413193965f, s, fmaf(2.6097574011f,  m, -1.2684380046f * l));
    float z2 = fmaf(1.707614701f,  s, fmaf(-0.7034186147f, m, 0.0041960863f  * l));

    // w = z @ M3
    Px p;
    p.r = fmaf(0.0474050234857193f, z2, fmaf(0.339523761133735f,  z1, 0.613130111351449f  * z0));
    p.g = fmaf(0.0134571284251877f, z2, fmaf(0.916356903394254f,  z1, 0.0701050973342151f * z0));
    p.b = fmaf(0.869782709459968f,  z2, fmaf(0.109559786350199f,  z1, 0.0205851228833001f * z0));
    return p;
}

__device__ __forceinline__ void do_quad(f4 xL, f4 xA, f4 xB,
                                        f4& oR, f4& oG, f4& oB) {
    Px p0 = oklab_px(xL.x, xA.x, xB.x);
    Px p1 = oklab_px(xL.y, xA.y, xB.y);
    Px p2 = oklab_px(xL.z, xA.z, xB.z);
    Px p3 = oklab_px(xL.w, xA.w, xB.w);
    oR.x = p0.r; oR.y = p1.r; oR.z = p2.r; oR.w = p3.r;
    oG.x = p0.g; oG.y = p1.g; oG.z = p2.g; oG.w = p3.g;
    oB.x = p0.b; oB.y = p1.b; oB.z = p2.b; oB.w = p3.b;
}

__global__ __launch_bounds__(256) void oklab_to_acescg_kernel(
    const f4* __restrict__ in, f4* __restrict__ out) {
    int t = blockIdx.x * blockDim.x + threadIdx.x;    // 0 .. 2^20-1
    // Adjacent pair: quads 2t and 2t+1 within one plane.
    int b = t >> 17;                 // t / (QP/2)
    int q = (t & (QP / 2 - 1)) * 2;  // even quad index within plane

    int iL = (b * 3 + 0) * QP + q;
    int iA = (b * 3 + 1) * QP + q;
    int iB = (b * 3 + 2) * QP + q;

    // Issue all 6 loads (3 streams x 2 adjacent float4) before dependent math.
    const f4 aL0 = in[iL], aL1 = in[iL + 1];
    const f4 aA0 = in[iA], aA1 = in[iA + 1];
    const f4 aB0 = in[iB], aB1 = in[iB + 1];

    f4 r0, g0, b0, r1, g1, b1;
    do_quad(aL0, aA0, aB0, r0, g0, b0);
    do_quad(aL1, aA1, aB1, r1, g1, b1);

    __builtin_nontemporal_store(r0, &out[iL]);
    __builtin_nontemporal_store(r1, &out[iL + 1]);
    __builtin_nontemporal_store(g0, &out[iA]);
    __builtin_nontemporal_store(g1, &out[iA + 1]);
    __builtin_nontemporal_store(b0, &out[iB]);
    __builtin_nontemporal_store(b1, &out[iB + 1]);
}

extern "C" void kernel_launch(void* const* d_in, const int* in_sizes, int n_in,
                              void* d_out, int out_size, void* d_ws, size_t ws_size,
                              hipStream_t stream) {
    const f4* in = (const f4*)d_in[0];
    f4* out = (f4*)d_out;
    int threads = 256;
    int blocks = NTHREADS / threads;   // 4096 blocks, exact coverage
    oklab_to_acescg_kernel<<<blocks, threads, 0, stream>>>(in, out);
}

// Round 5
// 36.054 us; speedup vs baseline: 1.2585x; 1.2585x over previous
//
#include <hip/hip_runtime.h>

// OKLab -> ACEScg: per-pixel 3-vector transform on [B=8, C=3, H=1024, W=1024] fp32.
// Memory-bound: 100.7 MB in + 100.7 MB out. R4: revert to R0 (best, 35.57 us) —
// grid-stride float4 per channel plane, per-instruction coalescing (lane i ->
// base + i*16). R3's adjacent-pair (lane stride 32B) broke coalescing: 45.4 us.
// Plateau evidence: R0 35.57 / R2 35.71 (NT stores + 2-quad ILP neutral) =
// 5.66 TB/s effective = 90% of measured 6.29 TB/s copy ceiling.

#define B_DIM 8
#define HW (1024 * 1024)
#define QP (HW / 4)                 // float4 quads per plane = 2^18
#define NQUADS (B_DIM * QP)         // total pixel-quads = 2^21

__device__ __forceinline__ void oklab_px(float L, float A, float Bv,
                                         float& r, float& g, float& b) {
    // y = x @ M1  (row-vector: y_j = sum_i x_i * M1[i][j])
    float y0 = fmaf(0.2158037573f,  Bv, fmaf(0.3963377774f,  A, L));
    float y1 = fmaf(-0.0638541728f, Bv, fmaf(-0.1055613458f, A, L));
    float y2 = fmaf(-1.291485548f,  Bv, fmaf(-0.0894841775f, A, L));

    // signed cube == plain cube
    float l = y0 * y0 * y0;
    float m = y1 * y1 * y1;
    float s = y2 * y2 * y2;

    // z = y @ M2
    float z0 = fmaf(0.2309699292f, s, fmaf(-3.3077115913f, m, 4.0767416621f  * l));
    float z1 = fmaf(-0.3413193965f, s, fmaf(2.6097574011f,  m, -1.2684380046f * l));
    float z2 = fmaf(1.707614701f,  s, fmaf(-0.7034186147f, m, 0.0041960863f  * l));

    // w = z @ M3
    r = fmaf(0.0474050234857193f, z2, fmaf(0.339523761133735f,  z1, 0.613130111351449f  * z0));
    g = fmaf(0.0134571284251877f, z2, fmaf(0.916356903394254f,  z1, 0.0701050973342151f * z0));
    b = fmaf(0.869782709459968f,  z2, fmaf(0.109559786350199f,  z1, 0.0205851228833001f * z0));
}

__global__ __launch_bounds__(256) void oklab_to_acescg_kernel(
    const float4* __restrict__ in, float4* __restrict__ out) {
    int idx = blockIdx.x * blockDim.x + threadIdx.x;
    int stride = gridDim.x * blockDim.x;
    for (int t = idx; t < NQUADS; t += stride) {
        int b = t >> 18;            // t / QP (QP = 2^18)
        int q = t & (QP - 1);       // t % QP
        const float4 xL = in[(b * 3 + 0) * QP + q];
        const float4 xA = in[(b * 3 + 1) * QP + q];
        const float4 xB = in[(b * 3 + 2) * QP + q];

        float4 oR, oG, oB;
        oklab_px(xL.x, xA.x, xB.x, oR.x, oG.x, oB.x);
        oklab_px(xL.y, xA.y, xB.y, oR.y, oG.y, oB.y);
        oklab_px(xL.z, xA.z, xB.z, oR.z, oG.z, oB.z);
        oklab_px(xL.w, xA.w, xB.w, oR.w, oG.w, oB.w);

        out[(b * 3 + 0) * QP + q] = oR;
        out[(b * 3 + 1) * QP + q] = oG;
        out[(b * 3 + 2) * QP + q] = oB;
    }
}

extern "C" void kernel_launch(void* const* d_in, const int* in_sizes, int n_in,
                              void* d_out, int out_size, void* d_ws, size_t ws_size,
                              hipStream_t stream) {
    const float4* in = (const float4*)d_in[0];
    float4* out = (float4*)d_out;
    int threads = 256;
    int blocks = 2048;
    oklab_to_acescg_kernel<<<blocks, threads, 0, stream>>>(in, out);
}